// Round 14
// baseline (154.359 us; speedup 1.0000x reference)
//
#include <hip/hip_runtime.h>
#include <math.h>

// N = 160000 = 256 * 625; four-step FFT decomposition.
// f1: pack w+i*o (float4), per-wave in-place DIF-625 -> G[n1][k2] (contiguous 512-B
//     runs per wave); zeroes E.
// f2: 16-k2 tile transpose-load of G (128-B lines), one row per wave (1024 thr),
//     pad8-swizzled in-place DIF-256 -> X[k2][k1], bin = 625*k1 + k2
// i1: one row per wave, sparse band load, pad8 swizzle, chained epilogue ->
//     coalesced fp32 H[n1][k2] writes   (R12 proven)
// i2: one wave per column, 2 fp32 columns prefetched, cached stage twiddles,
//     per-wave LDS partials, single barrier   (R12 proven)
constexpr int L      = 160000;
constexpr int BATCH  = 8;
constexpr int NB     = 8;
constexpr int NHOPS  = 156;
constexpr int NCHUNK = 155;
constexpr int RS     = 289;   // swizzled row stride
constexpr float TWO_PI = 6.28318530717958647692f;

__device__ __forceinline__ float2 cmulf(float2 a, float2 b) {
  return make_float2(a.x * b.x - a.y * b.y, a.x * b.y + a.y * b.x);
}

__device__ __forceinline__ float2 cisf(float a) {
  float s, c;
  __sincosf(a, &s, &c);
  return make_float2(c, s);
}

__device__ __forceinline__ int pad8(int i) { return i + (i >> 3); }

template <int SIGN>
__device__ __forceinline__ void bf4s(float2* v) {
  float2 t0 = make_float2(v[0].x + v[2].x, v[0].y + v[2].y);
  float2 t1 = make_float2(v[0].x - v[2].x, v[0].y - v[2].y);
  float2 t2 = make_float2(v[1].x + v[3].x, v[1].y + v[3].y);
  float2 t3 = make_float2(v[1].x - v[3].x, v[1].y - v[3].y);
  v[0] = make_float2(t0.x + t2.x, t0.y + t2.y);
  v[2] = make_float2(t0.x - t2.x, t0.y - t2.y);
  if constexpr (SIGN < 0) {
    v[1] = make_float2(t1.x + t3.y, t1.y - t3.x);
    v[3] = make_float2(t1.x - t3.y, t1.y + t3.x);
  } else {
    v[1] = make_float2(t1.x - t3.y, t1.y + t3.x);
    v[3] = make_float2(t1.x + t3.y, t1.y - t3.x);
  }
}

template <int SIGN>
__device__ __forceinline__ void bf5s(float2* v) {
  const float c1 = 0.30901699437494745f, s1 = 0.9510565162951535f;
  const float c2 = -0.8090169943749475f, s2 = 0.5877852522924731f;
  float2 t1 = make_float2(v[1].x + v[4].x, v[1].y + v[4].y);
  float2 t3 = make_float2(v[1].x - v[4].x, v[1].y - v[4].y);
  float2 t2 = make_float2(v[2].x + v[3].x, v[2].y + v[3].y);
  float2 t4 = make_float2(v[2].x - v[3].x, v[2].y - v[3].y);
  float2 a = make_float2(v[0].x + c1 * t1.x + c2 * t2.x, v[0].y + c1 * t1.y + c2 * t2.y);
  float2 b = make_float2(s1 * t3.x + s2 * t4.x, s1 * t3.y + s2 * t4.y);
  float2 c = make_float2(v[0].x + c2 * t1.x + c1 * t2.x, v[0].y + c2 * t1.y + c1 * t2.y);
  float2 d = make_float2(s2 * t3.x - s1 * t4.x, s2 * t3.y - s1 * t4.y);
  v[0] = make_float2(v[0].x + t1.x + t2.x, v[0].y + t1.y + t2.y);
  if constexpr (SIGN < 0) {
    v[1] = make_float2(a.x + b.y, a.y - b.x);
    v[4] = make_float2(a.x - b.y, a.y + b.x);
    v[2] = make_float2(c.x + d.y, c.y - d.x);
    v[3] = make_float2(c.x - d.y, c.y + d.x);
  } else {
    v[1] = make_float2(a.x - b.y, a.y + b.x);
    v[4] = make_float2(a.x + b.y, a.y - b.x);
    v[2] = make_float2(c.x - d.y, c.y + d.x);
    v[3] = make_float2(c.x + d.y, c.y - d.x);
  }
}

template <int R>
__device__ __forceinline__ void twchain(float2* v, float2 t1) {
  float2 t = t1;
  v[1] = cmulf(v[1], t);
#pragma unroll
  for (int r = 2; r < R; ++r) { t = cmulf(t, t1); v[r] = cmulf(v[r], t); }
}

__device__ __forceinline__ int rev3_5(int q) {
  int q5 = q / 5, q25 = q / 25;
  int d0 = q - 5 * q5, d1 = q5 - 5 * q25;
  return 25 * d0 + 5 * d1 + q25;
}

__device__ __forceinline__ int rev3_4(int q) {
  return ((q & 3) << 4) | (q & 12) | (q >> 4);
}

// ---------- in-place DIF-625 stage, chained twiddles ----------
template <int SUB, int SIGN>
__device__ __forceinline__ void dif5_ip_stage_c(float2* a, int ln) {
  int i1 = ln, i2 = ln + 64;
  bool g2 = (i2 < 125);
  int j1 = i1 % SUB, j2 = i2 % SUB;
  int b1 = (i1 / SUB) * (5 * SUB) + j1;
  int b2 = (i2 / SUB) * (5 * SUB) + j2;
  float2 u[5], v[5];
#pragma unroll
  for (int r = 0; r < 5; ++r) u[r] = a[b1 + SUB * r];
  if (g2) {
#pragma unroll
    for (int r = 0; r < 5; ++r) v[r] = a[b2 + SUB * r];
  }
  bf5s<SIGN>(u);
  twchain<5>(u, cisf((float)SIGN * (TWO_PI / (float)(5 * SUB)) * (float)j1));
  if (g2) {
    bf5s<SIGN>(v);
    twchain<5>(v, cisf((float)SIGN * (TWO_PI / (float)(5 * SUB)) * (float)j2));
  }
#pragma unroll
  for (int r = 0; r < 5; ++r) a[b1 + SUB * r] = u[r];
  if (g2) {
#pragma unroll
    for (int r = 0; r < 5; ++r) a[b2 + SUB * r] = v[r];
  }
}

template <int SUB>
__device__ __forceinline__ void dif5_ip_stage_t(float2* a, int ln, float2 t1a, float2 t1b) {
  int i1 = ln, i2 = ln + 64;
  bool g2 = (i2 < 125);
  int j1 = i1 % SUB, j2 = i2 % SUB;
  int b1 = (i1 / SUB) * (5 * SUB) + j1;
  int b2 = (i2 / SUB) * (5 * SUB) + j2;
  float2 u[5], v[5];
#pragma unroll
  for (int r = 0; r < 5; ++r) u[r] = a[b1 + SUB * r];
  if (g2) {
#pragma unroll
    for (int r = 0; r < 5; ++r) v[r] = a[b2 + SUB * r];
  }
  bf5s<1>(u);
  twchain<5>(u, t1a);
  if (g2) {
    bf5s<1>(v);
    twchain<5>(v, t1b);
  }
#pragma unroll
  for (int r = 0; r < 5; ++r) a[b1 + SUB * r] = u[r];
  if (g2) {
#pragma unroll
    for (int r = 0; r < 5; ++r) a[b2 + SUB * r] = v[r];
  }
}

template <int SIGN>
__device__ __forceinline__ void dif625_ip(float2* a, int ln) {
  dif5_ip_stage_c<125, SIGN>(a, ln);
  dif5_ip_stage_c<25, SIGN>(a, ln);
  dif5_ip_stage_c<5, SIGN>(a, ln);
  int q1 = ln, q2 = ln + 64;
  bool g2 = (q2 < 125);
  float2 u[5], v[5];
#pragma unroll
  for (int r = 0; r < 5; ++r) u[r] = a[5 * q1 + r];
  if (g2) {
#pragma unroll
    for (int r = 0; r < 5; ++r) v[r] = a[5 * q2 + r];
  }
  bf5s<SIGN>(u);
  if (g2) bf5s<SIGN>(v);
  int rv1 = rev3_5(q1), rv2 = rev3_5(q2);
#pragma unroll
  for (int r = 0; r < 5; ++r) a[125 * r + rv1] = u[r];
  if (g2) {
#pragma unroll
    for (int r = 0; r < 5; ++r) a[125 * r + rv2] = v[r];
  }
}

// ---------- in-place DIF-256, pad8-swizzled, chained twiddles ----------
template <int SIGN>
__device__ __forceinline__ void dif256sw_ip(float2* a, int ln) {
  {
    float2 u[4];
#pragma unroll
    for (int r = 0; r < 4; ++r) u[r] = a[pad8(ln + 64 * r)];
    bf4s<SIGN>(u);
    twchain<4>(u, cisf((float)SIGN * (TWO_PI / 256.0f) * (float)ln));
#pragma unroll
    for (int r = 0; r < 4; ++r) a[pad8(ln + 64 * r)] = u[r];
  }
  {
    int j = ln & 15, b = 64 * (ln >> 4) + j;
    float2 u[4];
#pragma unroll
    for (int r = 0; r < 4; ++r) u[r] = a[pad8(b + 16 * r)];
    bf4s<SIGN>(u);
    twchain<4>(u, cisf((float)SIGN * (TWO_PI / 64.0f) * (float)j));
#pragma unroll
    for (int r = 0; r < 4; ++r) a[pad8(b + 16 * r)] = u[r];
  }
  {
    int j = ln & 3, b = 16 * (ln >> 2) + j;
    float2 u[4];
#pragma unroll
    for (int r = 0; r < 4; ++r) u[r] = a[pad8(b + 4 * r)];
    bf4s<SIGN>(u);
    twchain<4>(u, cisf((float)SIGN * (TWO_PI / 16.0f) * (float)j));
#pragma unroll
    for (int r = 0; r < 4; ++r) a[pad8(b + 4 * r)] = u[r];
  }
  {
    float2 u[4];
#pragma unroll
    for (int r = 0; r < 4; ++r) u[r] = a[pad8(4 * ln + r)];
    bf4s<SIGN>(u);
    int rv = rev3_4(ln);
#pragma unroll
    for (int r = 0; r < 4; ++r) a[pad8(64 * r + rv)] = u[r];
  }
}

// ---------- F1: float4 pack, in-place DIF-625, contiguous G[n1][k2] store; zero E ----------
__global__ __launch_bounds__(256) void f1_kernel(const float* __restrict__ win,
                                                 const float* __restrict__ oin,
                                                 float2* __restrict__ G,
                                                 float* __restrict__ E) {
  __shared__ float2 A[4 * 625];    // 20 KB
  int blk = blockIdx.x;
  int gid = blk * 256 + threadIdx.x;
  if (gid < 2 * BATCH * NB * NHOPS) E[gid] = 0.0f;   // replaces memset launch
  int sig = blk >> 6, g = blk & 63;
  int n1base = g * 4;
  int tid = threadIdx.x;
  const float4* wp4 = (const float4*)(win + (size_t)sig * L);
  const float4* op4 = (const float4*)(oin + (size_t)sig * L);
  for (int r = tid; r < 625; r += 256) {
    float4 wv = wp4[r * 64 + g];
    float4 ov = op4[r * 64 + g];
    A[0 * 625 + r] = make_float2(wv.x, ov.x);
    A[1 * 625 + r] = make_float2(wv.y, ov.y);
    A[2 * 625 + r] = make_float2(wv.z, ov.z);
    A[3 * 625 + r] = make_float2(wv.w, ov.w);
  }
  __syncthreads();
  int wv_ = tid >> 6, ln = tid & 63;
  dif625_ip<-1>(A + wv_ * 625, ln);   // barrier-free; natural order out
  __syncthreads();
  // wave owns row cc = wv_; lanes sweep k2 contiguously -> 512-B runs, full lines
  int n1 = n1base + wv_;
  float w = -(TWO_PI / (float)L) * (float)n1;
  float2 t = cisf(w * (float)ln);
  float2 stp = cisf(w * 64.0f);
  float2* Gr = G + (size_t)sig * L + (size_t)n1 * 625;
  const float2* Ar = A + wv_ * 625;
  for (int k2 = ln; k2 < 625; k2 += 64) {
    Gr[k2] = cmulf(Ar[k2], t);
    t = cmulf(t, stp);
  }
}

// ---------- F2: 16-k2 tile transpose-load, one row per wave, -> X[k2][k1] ----------
__global__ __launch_bounds__(1024) void f2_kernel(const float2* __restrict__ G,
                                                  float2* __restrict__ X) {
  __shared__ float2 A[16 * RS];   // 36,992 B
  int blk = blockIdx.x;
  int sig = blk / 40, gr = blk % 40;
  int k2base = gr * 16;
  int tid = threadIdx.x;
  int wv = tid >> 6, ln = tid & 63;
  // transpose-load: 16 consecutive k2 per n1 -> 128-B lines
  for (int idx = tid; idx < 4096; idx += 1024) {
    int n1 = idx >> 4, cc = idx & 15;
    int k2 = k2base + cc;
    if (k2 < 625)
      A[cc * RS + pad8(n1)] = G[(size_t)sig * L + (size_t)n1 * 625 + k2];
  }
  __syncthreads();
  int k2 = k2base + wv;              // wave owns row wv
  float2* a = A + wv * RS;
  if (k2 < 625) dif256sw_ip<-1>(a, ln);
  __syncthreads();
  for (int idx = tid; idx < 4096; idx += 1024) {
    int row = idx >> 8, k1 = idx & 255;
    int k2e = k2base + row;
    if (k2e < 625) X[(size_t)sig * L + k2e * 256 + k1] = A[row * RS + pad8(k1)];
  }
}

// ---------- I1: one row per wave, sparse band load, pad8 swizzle, fp32 H writes ----------
__global__ __launch_bounds__(1024) void i1_kernel(const float2* __restrict__ X,
                                                  float2* __restrict__ H) {
  __shared__ float2 A[16 * RS];   // 36,992 B; 2 blocks/CU = 32 waves
  int blk = blockIdx.x;
  int gr = blk % 40, sb = blk / 40;
  int band = sb & 7, sig = sb >> 3;
  int k2base = gr * 16;
  int tid = threadIdx.x;
  int wv = tid >> 6, ln = tid & 63;
  int lo1, hi1, lo2, hi2;
  if (band < 7) {
    lo1 = 10000 * band + 1;        hi1 = 10000 * (band + 1);
    lo2 = L - 10000 * (band + 1);  hi2 = L - 10000 * band - 1;
  } else {
    lo1 = 70001; hi1 = 80000; lo2 = 80001; hi2 = 89999;
  }
  float2 zero = make_float2(0.0f, 0.0f);
  int k2 = k2base + wv;               // wave owns row wv
  float2* row = A + wv * RS;
  for (int k1 = ln; k1 < 256; k1 += 64) row[pad8(k1)] = zero;
  if (k2 < 625) {
    const float2* Xr = X + (size_t)sig * L + k2 * 256;
    int s1 = (lo1 - k2 + 624) / 625;
    int e1 = (hi1 - k2) / 625; if (e1 > 255) e1 = 255;
    int s2 = (lo2 - k2 + 624) / 625;
    int e2 = (hi2 - k2) / 625; if (e2 > 255) e2 = 255;
    int c1 = e1 - s1 + 1;
    int c2 = e2 - s2 + 1;
    if (ln < c1) { int k1 = s1 + ln; row[pad8(k1)] = Xr[k1]; }
    int l2 = ln - 32;
    if (l2 >= 0 && l2 < c2) { int k1 = s2 + l2; row[pad8(k1)] = Xr[k1]; }
    if (band == 7 && k2 == 0 && ln == 0) row[pad8(0)] = Xr[0];   // DC bin -> band 7
    dif256sw_ip<1>(row, ln);
  }
  __syncthreads();
  // epilogue: thread owns fixed k2e; 4 n1 per thread, chained step e^{i a0*64}
  size_t obase = (size_t)(sig * NB + band) * L;
  int cc = tid & 15, n1g = tid >> 4;
  int k2e = k2base + cc;
  if (k2e < 625) {
    float a0 = (TWO_PI / (float)L) * (float)k2e;
    float2 t = cisf(a0 * (float)n1g);
    float2 stp = cisf(a0 * 64.0f);
#pragma unroll
    for (int it = 0; it < 4; ++it) {
      int n1 = n1g + 64 * it;
      H[obase + (size_t)n1 * 625 + k2e] = cmulf(A[cc * RS + pad8(n1)], t);
      t = cmulf(t, stp);
    }
  }
}

// ---------- I2: one wave per column, 2 columns prefetched, cached twiddles ----------
__global__ __launch_bounds__(256) void i2_kernel(const float2* __restrict__ H,
                                                 float* __restrict__ E) {
  __shared__ float2 A[4 * 625];       // 20000 B
  __shared__ float P[4 * 2 * NHOPS];  // 4992 B
  int blk = blockIdx.x;               // grid = BATCH*NB*32 = 2048
  int g = blk & 31, sb = blk >> 5;
  int band = sb & 7, sig = sb >> 3;
  int tid = threadIdx.x;
  int wv = tid >> 6, ln = tid & 63;
  size_t base = (size_t)(sig * NB + band) * L;
  int n1A = 8 * g + wv, n1B = 8 * g + 4 + wv;
  const float2* HA = H + base + (size_t)n1A * 625;
  const float2* HB = H + base + (size_t)n1B * 625;
  int j1 = ln, j2 = ln + 64;
  bool g2 = (j2 < 125);
  float2 uA1[5], uA2[5], uB1[5], uB2[5];
#pragma unroll
  for (int r = 0; r < 5; ++r) uA1[r] = HA[j1 + 125 * r];
  if (g2) {
#pragma unroll
    for (int r = 0; r < 5; ++r) uA2[r] = HA[j2 + 125 * r];
  }
#pragma unroll
  for (int r = 0; r < 5; ++r) uB1[r] = HB[j1 + 125 * r];
  if (g2) {
#pragma unroll
    for (int r = 0; r < 5; ++r) uB2[r] = HB[j2 + 125 * r];
  }
  float2 tS1a = cisf((TWO_PI / 625.0f) * (float)j1);
  float2 tS1b = cisf((TWO_PI / 625.0f) * (float)j2);
  float2 tS2a = cisf((TWO_PI / 125.0f) * (float)(j1 % 25));
  float2 tS2b = cisf((TWO_PI / 125.0f) * (float)(j2 % 25));
  float2 tS3a = cisf((TWO_PI / 25.0f) * (float)(j1 % 5));
  float2 tS3b = cisf((TWO_PI / 25.0f) * (float)(j2 % 5));
  float2* a = A + wv * 625;
  float* Pw = P + wv * (2 * NHOPS);

  // ---- column A ----
  bf5s<1>(uA1);
  twchain<5>(uA1, tS1a);
#pragma unroll
  for (int r = 0; r < 5; ++r) a[j1 + 125 * r] = uA1[r];
  if (g2) {
    bf5s<1>(uA2);
    twchain<5>(uA2, tS1b);
#pragma unroll
    for (int r = 0; r < 5; ++r) a[j2 + 125 * r] = uA2[r];
  }
  dif5_ip_stage_t<25>(a, ln, tS2a, tS2b);
  dif5_ip_stage_t<5>(a, ln, tS3a, tS3b);
  {
    float2 u[5], v[5];
#pragma unroll
    for (int r = 0; r < 5; ++r) u[r] = a[5 * j1 + r];
    if (g2) {
#pragma unroll
      for (int r = 0; r < 5; ++r) v[r] = a[5 * j2 + r];
    }
    bf5s<1>(u);
    if (g2) bf5s<1>(v);
    int rv1 = rev3_5(j1), rv2 = rev3_5(j2);
#pragma unroll
    for (int r = 0; r < 5; ++r) a[125 * r + rv1] = u[r];
    if (g2) {
#pragma unroll
      for (int r = 0; r < 5; ++r) a[125 * r + rv2] = v[r];
    }
  }
  for (int h = ln; h < NHOPS; h += 64) {
    float ex = 0.0f, ey = 0.0f;
#pragma unroll
    for (int d = 0; d < 4; ++d) {
      float2 z = a[4 * h + d];
      ex += z.x * z.x;
      ey += z.y * z.y;
    }
    Pw[h] = ex;
    Pw[NHOPS + h] = ey;
  }

  // ---- column B (same twiddles) ----
  bf5s<1>(uB1);
  twchain<5>(uB1, tS1a);
#pragma unroll
  for (int r = 0; r < 5; ++r) a[j1 + 125 * r] = uB1[r];
  if (g2) {
    bf5s<1>(uB2);
    twchain<5>(uB2, tS1b);
#pragma unroll
    for (int r = 0; r < 5; ++r) a[j2 + 125 * r] = uB2[r];
  }
  dif5_ip_stage_t<25>(a, ln, tS2a, tS2b);
  dif5_ip_stage_t<5>(a, ln, tS3a, tS3b);
  {
    float2 u[5], v[5];
#pragma unroll
    for (int r = 0; r < 5; ++r) u[r] = a[5 * j1 + r];
    if (g2) {
#pragma unroll
      for (int r = 0; r < 5; ++r) v[r] = a[5 * j2 + r];
    }
    bf5s<1>(u);
    if (g2) bf5s<1>(v);
    int rv1 = rev3_5(j1), rv2 = rev3_5(j2);
#pragma unroll
    for (int r = 0; r < 5; ++r) a[125 * r + rv1] = u[r];
    if (g2) {
#pragma unroll
      for (int r = 0; r < 5; ++r) a[125 * r + rv2] = v[r];
    }
  }
  for (int h = ln; h < NHOPS; h += 64) {
    float ex = 0.0f, ey = 0.0f;
#pragma unroll
    for (int d = 0; d < 4; ++d) {
      float2 z = a[4 * h + d];
      ex += z.x * z.x;
      ey += z.y * z.y;
    }
    Pw[h] += ex;
    Pw[NHOPS + h] += ey;
  }
  __syncthreads();   // the only block-wide barrier
  int eb = (sig * NB + band) * NHOPS;
  for (int idx = tid; idx < 2 * NHOPS; idx += 256) {
    float v = P[idx] + P[2 * NHOPS + idx] + P[4 * NHOPS + idx] + P[6 * NHOPS + idx];
    int comp = idx / NHOPS, h = idx - comp * NHOPS;
    atomicAdd(&E[comp * (BATCH * NB * NHOPS) + eb + h], v);
  }
}

// ---------- finalize: loudness, diff, softmax-weighted sum (1/L^2 folded into SC) ----------
__global__ __launch_bounds__(1024) void finalize_kernel(const float* __restrict__ E,
                                                        float* __restrict__ out) {
  constexpr int ND = BATCH * NB * NCHUNK;  // 9920
  constexpr float SC = (1.0f / 2048.0f) / ((float)L * (float)L);
  __shared__ float diffs[ND];
  __shared__ float sred[1024];
  int tid = threadIdx.x;
  for (int idx = tid; idx < ND; idx += 1024) {
    int sb = idx / NCHUNK;
    int k = idx - sb * NCHUNK;
    float msw = (E[sb * NHOPS + k] + E[sb * NHOPS + k + 1]) * SC;
    float mso = (E[64 * NHOPS + sb * NHOPS + k] + E[64 * NHOPS + sb * NHOPS + k + 1]) * SC;
    float lw = -0.691f + 10.0f * log10f(msw + 1e-12f);
    float lo = -0.691f + 10.0f * log10f(mso + 1e-12f);
    diffs[idx] = lw - lo;
  }
  __syncthreads();
  float mx = -3.4e38f;
  for (int idx = tid; idx < ND; idx += 1024) mx = fmaxf(mx, diffs[idx]);
  sred[tid] = mx;
  __syncthreads();
  for (int s = 512; s > 0; s >>= 1) {
    if (tid < s) sred[tid] = fmaxf(sred[tid], sred[tid + s]);
    __syncthreads();
  }
  float gmax = sred[0];
  __syncthreads();
  float se = 0.0f, swd = 0.0f;
  for (int idx = tid; idx < ND; idx += 1024) {
    float d = diffs[idx];
    float e = expf(d - gmax);
    se += e;
    swd += d * e;
  }
  sred[tid] = se; __syncthreads();
  for (int s = 512; s > 0; s >>= 1) { if (tid < s) sred[tid] += sred[tid + s]; __syncthreads(); }
  float tot = sred[0];
  __syncthreads();
  sred[tid] = swd; __syncthreads();
  for (int s = 512; s > 0; s >>= 1) { if (tid < s) sred[tid] += sred[tid + s]; __syncthreads(); }
  if (tid == 0) out[0] = sred[0] / tot;
}

extern "C" void kernel_launch(void* const* d_in, const int* in_sizes, int n_in,
                              void* d_out, int out_size, void* d_ws, size_t ws_size,
                              hipStream_t stream) {
  (void)in_sizes; (void)n_in; (void)out_size; (void)ws_size;
  char* ws = (char*)d_ws;
  float2* G = (float2*)ws;                        // 10,240,000 B
  float2* X = (float2*)(ws + 10240000);           // 10,240,000 B
  float2* H = (float2*)(ws + 20480000);           // 81,920,000 B
  float*  E = (float*)(ws + 102400000);           // 79,872 B [2][64][156]
  const float* w = (const float*)d_in[0];
  const float* o = (const float*)d_in[1];

  f1_kernel<<<dim3(BATCH * 64), dim3(256), 0, stream>>>(w, o, G, E);
  f2_kernel<<<dim3(BATCH * 40), dim3(1024), 0, stream>>>(G, X);
  i1_kernel<<<dim3(BATCH * NB * 40), dim3(1024), 0, stream>>>(X, H);
  i2_kernel<<<dim3(BATCH * NB * 32), dim3(256), 0, stream>>>(H, E);
  finalize_kernel<<<dim3(1), dim3(1024), 0, stream>>>(E, (float*)d_out);
}

// Round 15
// 147.939 us; speedup vs baseline: 1.0434x; 1.0434x over previous
//
#include <hip/hip_runtime.h>
#include <hip/hip_fp16.h>
#include <math.h>

// N = 160000 = 256 * 625; four-step FFT decomposition.
// R15 = R12 structure (best measured f1/f2) + fp16 H (measured -3.2 us).
// f1: pack w+i*o (float4), per-wave in-place DIF-625 (chained twiddles) -> G[k2][n1];
//     zeroes E. Epilogue twiddle chained over k2 steps of 64.
// f2: per-wave in-place DIF-256, pad8 LDS swizzle -> X[k2][k1], bin = 625*k1 + k2
// i1: 1024-thr blocks, one row per wave, sparse band load, pad8 swizzle, chained
//     epilogue -> coalesced fp16 H[n1][k2] writes (scaled by 1/L)
// i2: one wave per column, 2 fp16 columns prefetched, cached stage twiddles,
//     per-wave LDS partials, single barrier.
constexpr int L      = 160000;
constexpr int BATCH  = 8;
constexpr int NB     = 8;
constexpr int NHOPS  = 156;
constexpr int NCHUNK = 155;
constexpr int RS     = 289;   // swizzled row stride
constexpr float TWO_PI = 6.28318530717958647692f;
constexpr float INVL = 1.0f / (float)L;

__device__ __forceinline__ float2 cmulf(float2 a, float2 b) {
  return make_float2(a.x * b.x - a.y * b.y, a.x * b.y + a.y * b.x);
}

__device__ __forceinline__ float2 cisf(float a) {
  float s, c;
  __sincosf(a, &s, &c);
  return make_float2(c, s);
}

__device__ __forceinline__ int pad8(int i) { return i + (i >> 3); }

template <int SIGN>
__device__ __forceinline__ void bf4s(float2* v) {
  float2 t0 = make_float2(v[0].x + v[2].x, v[0].y + v[2].y);
  float2 t1 = make_float2(v[0].x - v[2].x, v[0].y - v[2].y);
  float2 t2 = make_float2(v[1].x + v[3].x, v[1].y + v[3].y);
  float2 t3 = make_float2(v[1].x - v[3].x, v[1].y - v[3].y);
  v[0] = make_float2(t0.x + t2.x, t0.y + t2.y);
  v[2] = make_float2(t0.x - t2.x, t0.y - t2.y);
  if constexpr (SIGN < 0) {
    v[1] = make_float2(t1.x + t3.y, t1.y - t3.x);
    v[3] = make_float2(t1.x - t3.y, t1.y + t3.x);
  } else {
    v[1] = make_float2(t1.x - t3.y, t1.y + t3.x);
    v[3] = make_float2(t1.x + t3.y, t1.y - t3.x);
  }
}

template <int SIGN>
__device__ __forceinline__ void bf5s(float2* v) {
  const float c1 = 0.30901699437494745f, s1 = 0.9510565162951535f;
  const float c2 = -0.8090169943749475f, s2 = 0.5877852522924731f;
  float2 t1 = make_float2(v[1].x + v[4].x, v[1].y + v[4].y);
  float2 t3 = make_float2(v[1].x - v[4].x, v[1].y - v[4].y);
  float2 t2 = make_float2(v[2].x + v[3].x, v[2].y + v[3].y);
  float2 t4 = make_float2(v[2].x - v[3].x, v[2].y - v[3].y);
  float2 a = make_float2(v[0].x + c1 * t1.x + c2 * t2.x, v[0].y + c1 * t1.y + c2 * t2.y);
  float2 b = make_float2(s1 * t3.x + s2 * t4.x, s1 * t3.y + s2 * t4.y);
  float2 c = make_float2(v[0].x + c2 * t1.x + c1 * t2.x, v[0].y + c2 * t1.y + c1 * t2.y);
  float2 d = make_float2(s2 * t3.x - s1 * t4.x, s2 * t3.y - s1 * t4.y);
  v[0] = make_float2(v[0].x + t1.x + t2.x, v[0].y + t1.y + t2.y);
  if constexpr (SIGN < 0) {
    v[1] = make_float2(a.x + b.y, a.y - b.x);
    v[4] = make_float2(a.x - b.y, a.y + b.x);
    v[2] = make_float2(c.x + d.y, c.y - d.x);
    v[3] = make_float2(c.x - d.y, c.y + d.x);
  } else {
    v[1] = make_float2(a.x - b.y, a.y + b.x);
    v[4] = make_float2(a.x + b.y, a.y - b.x);
    v[2] = make_float2(c.x - d.y, c.y + d.x);
    v[3] = make_float2(c.x + d.y, c.y - d.x);
  }
}

template <int R>
__device__ __forceinline__ void twchain(float2* v, float2 t1) {
  float2 t = t1;
  v[1] = cmulf(v[1], t);
#pragma unroll
  for (int r = 2; r < R; ++r) { t = cmulf(t, t1); v[r] = cmulf(v[r], t); }
}

__device__ __forceinline__ int rev3_5(int q) {
  int q5 = q / 5, q25 = q / 25;
  int d0 = q - 5 * q5, d1 = q5 - 5 * q25;
  return 25 * d0 + 5 * d1 + q25;
}

__device__ __forceinline__ int rev3_4(int q) {
  return ((q & 3) << 4) | (q & 12) | (q >> 4);
}

// ---------- in-place DIF-625 stage, chained twiddles ----------
template <int SUB, int SIGN>
__device__ __forceinline__ void dif5_ip_stage_c(float2* a, int ln) {
  int i1 = ln, i2 = ln + 64;
  bool g2 = (i2 < 125);
  int j1 = i1 % SUB, j2 = i2 % SUB;
  int b1 = (i1 / SUB) * (5 * SUB) + j1;
  int b2 = (i2 / SUB) * (5 * SUB) + j2;
  float2 u[5], v[5];
#pragma unroll
  for (int r = 0; r < 5; ++r) u[r] = a[b1 + SUB * r];
  if (g2) {
#pragma unroll
    for (int r = 0; r < 5; ++r) v[r] = a[b2 + SUB * r];
  }
  bf5s<SIGN>(u);
  twchain<5>(u, cisf((float)SIGN * (TWO_PI / (float)(5 * SUB)) * (float)j1));
  if (g2) {
    bf5s<SIGN>(v);
    twchain<5>(v, cisf((float)SIGN * (TWO_PI / (float)(5 * SUB)) * (float)j2));
  }
#pragma unroll
  for (int r = 0; r < 5; ++r) a[b1 + SUB * r] = u[r];
  if (g2) {
#pragma unroll
    for (int r = 0; r < 5; ++r) a[b2 + SUB * r] = v[r];
  }
}

template <int SUB>
__device__ __forceinline__ void dif5_ip_stage_t(float2* a, int ln, float2 t1a, float2 t1b) {
  int i1 = ln, i2 = ln + 64;
  bool g2 = (i2 < 125);
  int j1 = i1 % SUB, j2 = i2 % SUB;
  int b1 = (i1 / SUB) * (5 * SUB) + j1;
  int b2 = (i2 / SUB) * (5 * SUB) + j2;
  float2 u[5], v[5];
#pragma unroll
  for (int r = 0; r < 5; ++r) u[r] = a[b1 + SUB * r];
  if (g2) {
#pragma unroll
    for (int r = 0; r < 5; ++r) v[r] = a[b2 + SUB * r];
  }
  bf5s<1>(u);
  twchain<5>(u, t1a);
  if (g2) {
    bf5s<1>(v);
    twchain<5>(v, t1b);
  }
#pragma unroll
  for (int r = 0; r < 5; ++r) a[b1 + SUB * r] = u[r];
  if (g2) {
#pragma unroll
    for (int r = 0; r < 5; ++r) a[b2 + SUB * r] = v[r];
  }
}

template <int SIGN>
__device__ __forceinline__ void dif625_ip(float2* a, int ln) {
  dif5_ip_stage_c<125, SIGN>(a, ln);
  dif5_ip_stage_c<25, SIGN>(a, ln);
  dif5_ip_stage_c<5, SIGN>(a, ln);
  int q1 = ln, q2 = ln + 64;
  bool g2 = (q2 < 125);
  float2 u[5], v[5];
#pragma unroll
  for (int r = 0; r < 5; ++r) u[r] = a[5 * q1 + r];
  if (g2) {
#pragma unroll
    for (int r = 0; r < 5; ++r) v[r] = a[5 * q2 + r];
  }
  bf5s<SIGN>(u);
  if (g2) bf5s<SIGN>(v);
  int rv1 = rev3_5(q1), rv2 = rev3_5(q2);
#pragma unroll
  for (int r = 0; r < 5; ++r) a[125 * r + rv1] = u[r];
  if (g2) {
#pragma unroll
    for (int r = 0; r < 5; ++r) a[125 * r + rv2] = v[r];
  }
}

// ---------- in-place DIF-256, pad8-swizzled, chained twiddles ----------
template <int SIGN>
__device__ __forceinline__ void dif256sw_ip(float2* a, int ln) {
  {
    float2 u[4];
#pragma unroll
    for (int r = 0; r < 4; ++r) u[r] = a[pad8(ln + 64 * r)];
    bf4s<SIGN>(u);
    twchain<4>(u, cisf((float)SIGN * (TWO_PI / 256.0f) * (float)ln));
#pragma unroll
    for (int r = 0; r < 4; ++r) a[pad8(ln + 64 * r)] = u[r];
  }
  {
    int j = ln & 15, b = 64 * (ln >> 4) + j;
    float2 u[4];
#pragma unroll
    for (int r = 0; r < 4; ++r) u[r] = a[pad8(b + 16 * r)];
    bf4s<SIGN>(u);
    twchain<4>(u, cisf((float)SIGN * (TWO_PI / 64.0f) * (float)j));
#pragma unroll
    for (int r = 0; r < 4; ++r) a[pad8(b + 16 * r)] = u[r];
  }
  {
    int j = ln & 3, b = 16 * (ln >> 2) + j;
    float2 u[4];
#pragma unroll
    for (int r = 0; r < 4; ++r) u[r] = a[pad8(b + 4 * r)];
    bf4s<SIGN>(u);
    twchain<4>(u, cisf((float)SIGN * (TWO_PI / 16.0f) * (float)j));
#pragma unroll
    for (int r = 0; r < 4; ++r) a[pad8(b + 4 * r)] = u[r];
  }
  {
    float2 u[4];
#pragma unroll
    for (int r = 0; r < 4; ++r) u[r] = a[pad8(4 * ln + r)];
    bf4s<SIGN>(u);
    int rv = rev3_4(ln);
#pragma unroll
    for (int r = 0; r < 4; ++r) a[pad8(64 * r + rv)] = u[r];
  }
}

// ---------- F1: float4 pack, in-place DIF-625 (chained), chained epilogue; zero E ----------
__global__ __launch_bounds__(256) void f1_kernel(const float* __restrict__ win,
                                                 const float* __restrict__ oin,
                                                 float2* __restrict__ G,
                                                 float* __restrict__ E) {
  __shared__ float2 A[4 * 625];    // 20 KB
  int blk = blockIdx.x;
  int gid = blk * 256 + threadIdx.x;
  if (gid < 2 * BATCH * NB * NHOPS) E[gid] = 0.0f;   // replaces memset launch
  int sig = blk >> 6, g = blk & 63;
  int n1base = g * 4;
  int tid = threadIdx.x;
  const float4* wp4 = (const float4*)(win + (size_t)sig * L);
  const float4* op4 = (const float4*)(oin + (size_t)sig * L);
  for (int r = tid; r < 625; r += 256) {
    float4 wv = wp4[r * 64 + g];
    float4 ov = op4[r * 64 + g];
    A[0 * 625 + r] = make_float2(wv.x, ov.x);
    A[1 * 625 + r] = make_float2(wv.y, ov.y);
    A[2 * 625 + r] = make_float2(wv.z, ov.z);
    A[3 * 625 + r] = make_float2(wv.w, ov.w);
  }
  __syncthreads();
  int wv_ = tid >> 6, ln = tid & 63;
  dif625_ip<-1>(A + wv_ * 625, ln);   // barrier-free; natural order out
  __syncthreads();
  // chained epilogue: cc fixed, k2 steps by 64
  int cc = tid & 3, k20 = tid >> 2;
  int n1 = n1base + cc;
  float w = -(TWO_PI / (float)L) * (float)n1;
  float2 t = cisf(w * (float)k20);
  float2 stp = cisf(w * 64.0f);
  for (int k2 = k20; k2 < 625; k2 += 64) {
    G[(size_t)sig * L + k2 * 256 + n1] = cmulf(A[cc * 625 + k2], t);
    t = cmulf(t, stp);
  }
}

// ---------- F2: per-wave in-place DIF-256 (pad8), -> X[k2][k1] ----------
__global__ __launch_bounds__(256) void f2_kernel(const float2* __restrict__ G,
                                                 float2* __restrict__ X) {
  __shared__ float2 A[4 * RS];
  int blk = blockIdx.x;
  int sig = blk / 157, gr = blk % 157;
  int k2base = gr * 4;
  int tid = threadIdx.x;
  int wv = tid >> 6, ln = tid & 63;
  int k2 = k2base + wv;
  float2* a = A + wv * RS;
  if (k2 < 625) {
#pragma unroll
    for (int r = 0; r < 4; ++r)
      a[pad8(ln + 64 * r)] = G[(size_t)sig * L + k2 * 256 + ln + 64 * r];
    dif256sw_ip<-1>(a, ln);
  }
  __syncthreads();
  for (int idx = tid; idx < 1024; idx += 256) {
    int row = idx >> 8, k1 = idx & 255;
    int k2e = k2base + row;
    if (k2e < 625) X[(size_t)sig * L + k2e * 256 + k1] = A[row * RS + pad8(k1)];
  }
}

// ---------- I1: 1024 thr, one row per wave, sparse band load, pad8 swizzle,
//              chained epilogue -> coalesced fp16 H[n1][k2] writes ----------
__global__ __launch_bounds__(1024) void i1_kernel(const float2* __restrict__ X,
                                                  __half2* __restrict__ H) {
  __shared__ float2 A[16 * RS];   // 36,992 B; 2 blocks/CU = 32 waves
  int blk = blockIdx.x;
  int gr = blk % 40, sb = blk / 40;
  int band = sb & 7, sig = sb >> 3;
  int k2base = gr * 16;
  int tid = threadIdx.x;
  int wv = tid >> 6, ln = tid & 63;
  int lo1, hi1, lo2, hi2;
  if (band < 7) {
    lo1 = 10000 * band + 1;        hi1 = 10000 * (band + 1);
    lo2 = L - 10000 * (band + 1);  hi2 = L - 10000 * band - 1;
  } else {
    lo1 = 70001; hi1 = 80000; lo2 = 80001; hi2 = 89999;
  }
  float2 zero = make_float2(0.0f, 0.0f);
  int k2 = k2base + wv;               // wave owns row wv
  float2* row = A + wv * RS;
  for (int k1 = ln; k1 < 256; k1 += 64) row[pad8(k1)] = zero;   // same wave: in-order
  if (k2 < 625) {
    const float2* Xr = X + (size_t)sig * L + k2 * 256;
    int s1 = (lo1 - k2 + 624) / 625;
    int e1 = (hi1 - k2) / 625; if (e1 > 255) e1 = 255;
    int s2 = (lo2 - k2 + 624) / 625;
    int e2 = (hi2 - k2) / 625; if (e2 > 255) e2 = 255;
    int c1 = e1 - s1 + 1;
    int c2 = e2 - s2 + 1;
    if (ln < c1) { int k1 = s1 + ln; row[pad8(k1)] = Xr[k1]; }
    int l2 = ln - 32;
    if (l2 >= 0 && l2 < c2) { int k1 = s2 + l2; row[pad8(k1)] = Xr[k1]; }
    if (band == 7 && k2 == 0 && ln == 0) row[pad8(0)] = Xr[0];   // DC bin -> band 7
    dif256sw_ip<1>(row, ln);   // barrier-free inverse, natural order out
  }
  __syncthreads();
  // epilogue: thread owns fixed k2e; 4 n1 per thread, chained step e^{i a0*64}
  size_t obase = (size_t)(sig * NB + band) * L;
  int cc = tid & 15, n1g = tid >> 4;   // n1g in [0,64)
  int k2e = k2base + cc;
  if (k2e < 625) {
    float a0 = (TWO_PI / (float)L) * (float)k2e;
    float2 t = cisf(a0 * (float)n1g);
    float2 stp = cisf(a0 * 64.0f);
#pragma unroll
    for (int it = 0; it < 4; ++it) {
      int n1 = n1g + 64 * it;
      float2 val = cmulf(A[cc * RS + pad8(n1)], t);
      H[obase + (size_t)n1 * 625 + k2e] = __floats2half2_rn(val.x * INVL, val.y * INVL);
      t = cmulf(t, stp);
    }
  }
}

// ---------- I2: one wave per column, 2 fp16 columns prefetched, cached twiddles,
//              per-wave LDS partials, single barrier ----------
__global__ __launch_bounds__(256) void i2_kernel(const __half2* __restrict__ H,
                                                 float* __restrict__ E) {
  __shared__ float2 A[4 * 625];       // 20000 B
  __shared__ float P[4 * 2 * NHOPS];  // 4992 B
  int blk = blockIdx.x;               // grid = BATCH*NB*32 = 2048
  int g = blk & 31, sb = blk >> 5;
  int band = sb & 7, sig = sb >> 3;
  int tid = threadIdx.x;
  int wv = tid >> 6, ln = tid & 63;
  size_t base = (size_t)(sig * NB + band) * L;
  int n1A = 8 * g + wv, n1B = 8 * g + 4 + wv;
  const __half2* HA = H + base + (size_t)n1A * 625;
  const __half2* HB = H + base + (size_t)n1B * 625;
  int j1 = ln, j2 = ln + 64;
  bool g2 = (j2 < 125);
  __half2 hA1[5], hA2[5], hB1[5], hB2[5];
#pragma unroll
  for (int r = 0; r < 5; ++r) hA1[r] = HA[j1 + 125 * r];
  if (g2) {
#pragma unroll
    for (int r = 0; r < 5; ++r) hA2[r] = HA[j2 + 125 * r];
  }
#pragma unroll
  for (int r = 0; r < 5; ++r) hB1[r] = HB[j1 + 125 * r];
  if (g2) {
#pragma unroll
    for (int r = 0; r < 5; ++r) hB2[r] = HB[j2 + 125 * r];
  }
  float2 tS1a = cisf((TWO_PI / 625.0f) * (float)j1);
  float2 tS1b = cisf((TWO_PI / 625.0f) * (float)j2);
  float2 tS2a = cisf((TWO_PI / 125.0f) * (float)(j1 % 25));
  float2 tS2b = cisf((TWO_PI / 125.0f) * (float)(j2 % 25));
  float2 tS3a = cisf((TWO_PI / 25.0f) * (float)(j1 % 5));
  float2 tS3b = cisf((TWO_PI / 25.0f) * (float)(j2 % 5));
  float2* a = A + wv * 625;
  float* Pw = P + wv * (2 * NHOPS);

  // ---- column A ----
  {
    float2 u[5];
#pragma unroll
    for (int r = 0; r < 5; ++r) u[r] = __half22float2(hA1[r]);
    bf5s<1>(u);
    twchain<5>(u, tS1a);
#pragma unroll
    for (int r = 0; r < 5; ++r) a[j1 + 125 * r] = u[r];
    if (g2) {
      float2 v[5];
#pragma unroll
      for (int r = 0; r < 5; ++r) v[r] = __half22float2(hA2[r]);
      bf5s<1>(v);
      twchain<5>(v, tS1b);
#pragma unroll
      for (int r = 0; r < 5; ++r) a[j2 + 125 * r] = v[r];
    }
  }
  dif5_ip_stage_t<25>(a, ln, tS2a, tS2b);
  dif5_ip_stage_t<5>(a, ln, tS3a, tS3b);
  {
    float2 u[5], v[5];
#pragma unroll
    for (int r = 0; r < 5; ++r) u[r] = a[5 * j1 + r];
    if (g2) {
#pragma unroll
      for (int r = 0; r < 5; ++r) v[r] = a[5 * j2 + r];
    }
    bf5s<1>(u);
    if (g2) bf5s<1>(v);
    int rv1 = rev3_5(j1), rv2 = rev3_5(j2);
#pragma unroll
    for (int r = 0; r < 5; ++r) a[125 * r + rv1] = u[r];
    if (g2) {
#pragma unroll
      for (int r = 0; r < 5; ++r) a[125 * r + rv2] = v[r];
    }
  }
  for (int h = ln; h < NHOPS; h += 64) {
    float ex = 0.0f, ey = 0.0f;
#pragma unroll
    for (int d = 0; d < 4; ++d) {
      float2 z = a[4 * h + d];
      ex += z.x * z.x;
      ey += z.y * z.y;
    }
    Pw[h] = ex;
    Pw[NHOPS + h] = ey;
  }

  // ---- column B (same twiddles) ----
  {
    float2 u[5];
#pragma unroll
    for (int r = 0; r < 5; ++r) u[r] = __half22float2(hB1[r]);
    bf5s<1>(u);
    twchain<5>(u, tS1a);
#pragma unroll
    for (int r = 0; r < 5; ++r) a[j1 + 125 * r] = u[r];
    if (g2) {
      float2 v[5];
#pragma unroll
      for (int r = 0; r < 5; ++r) v[r] = __half22float2(hB2[r]);
      bf5s<1>(v);
      twchain<5>(v, tS1b);
#pragma unroll
      for (int r = 0; r < 5; ++r) a[j2 + 125 * r] = v[r];
    }
  }
  dif5_ip_stage_t<25>(a, ln, tS2a, tS2b);
  dif5_ip_stage_t<5>(a, ln, tS3a, tS3b);
  {
    float2 u[5], v[5];
#pragma unroll
    for (int r = 0; r < 5; ++r) u[r] = a[5 * j1 + r];
    if (g2) {
#pragma unroll
      for (int r = 0; r < 5; ++r) v[r] = a[5 * j2 + r];
    }
    bf5s<1>(u);
    if (g2) bf5s<1>(v);
    int rv1 = rev3_5(j1), rv2 = rev3_5(j2);
#pragma unroll
    for (int r = 0; r < 5; ++r) a[125 * r + rv1] = u[r];
    if (g2) {
#pragma unroll
      for (int r = 0; r < 5; ++r) a[125 * r + rv2] = v[r];
    }
  }
  for (int h = ln; h < NHOPS; h += 64) {
    float ex = 0.0f, ey = 0.0f;
#pragma unroll
    for (int d = 0; d < 4; ++d) {
      float2 z = a[4 * h + d];
      ex += z.x * z.x;
      ey += z.y * z.y;
    }
    Pw[h] += ex;
    Pw[NHOPS + h] += ey;
  }
  __syncthreads();   // the only block-wide barrier
  int eb = (sig * NB + band) * NHOPS;
  for (int idx = tid; idx < 2 * NHOPS; idx += 256) {
    float v = P[idx] + P[2 * NHOPS + idx] + P[4 * NHOPS + idx] + P[6 * NHOPS + idx];
    int comp = idx / NHOPS, h = idx - comp * NHOPS;
    atomicAdd(&E[comp * (BATCH * NB * NHOPS) + eb + h], v);
  }
}

// ---------- finalize: loudness, diff, softmax (H pre-scaled by 1/L -> SC = 1/2048) ----------
__global__ __launch_bounds__(1024) void finalize_kernel(const float* __restrict__ E,
                                                        float* __restrict__ out) {
  constexpr int ND = BATCH * NB * NCHUNK;  // 9920
  constexpr float SC = 1.0f / 2048.0f;
  __shared__ float diffs[ND];
  __shared__ float sred[1024];
  int tid = threadIdx.x;
  for (int idx = tid; idx < ND; idx += 1024) {
    int sb = idx / NCHUNK;
    int k = idx - sb * NCHUNK;
    float msw = (E[sb * NHOPS + k] + E[sb * NHOPS + k + 1]) * SC;
    float mso = (E[64 * NHOPS + sb * NHOPS + k] + E[64 * NHOPS + sb * NHOPS + k + 1]) * SC;
    float lw = -0.691f + 10.0f * log10f(msw + 1e-12f);
    float lo = -0.691f + 10.0f * log10f(mso + 1e-12f);
    diffs[idx] = lw - lo;
  }
  __syncthreads();
  float mx = -3.4e38f;
  for (int idx = tid; idx < ND; idx += 1024) mx = fmaxf(mx, diffs[idx]);
  sred[tid] = mx;
  __syncthreads();
  for (int s = 512; s > 0; s >>= 1) {
    if (tid < s) sred[tid] = fmaxf(sred[tid], sred[tid + s]);
    __syncthreads();
  }
  float gmax = sred[0];
  __syncthreads();
  float se = 0.0f, swd = 0.0f;
  for (int idx = tid; idx < ND; idx += 1024) {
    float d = diffs[idx];
    float e = expf(d - gmax);
    se += e;
    swd += d * e;
  }
  sred[tid] = se; __syncthreads();
  for (int s = 512; s > 0; s >>= 1) { if (tid < s) sred[tid] += sred[tid + s]; __syncthreads(); }
  float tot = sred[0];
  __syncthreads();
  sred[tid] = swd; __syncthreads();
  for (int s = 512; s > 0; s >>= 1) { if (tid < s) sred[tid] += sred[tid + s]; __syncthreads(); }
  if (tid == 0) out[0] = sred[0] / tot;
}

extern "C" void kernel_launch(void* const* d_in, const int* in_sizes, int n_in,
                              void* d_out, int out_size, void* d_ws, size_t ws_size,
                              hipStream_t stream) {
  (void)in_sizes; (void)n_in; (void)out_size; (void)ws_size;
  char* ws = (char*)d_ws;
  float2*  G = (float2*)ws;                        // 10,240,000 B
  float2*  X = (float2*)(ws + 10240000);           // 10,240,000 B
  __half2* H = (__half2*)(ws + 20480000);          // 40,960,000 B (fp16)
  float*   E = (float*)(ws + 61440000);            // 79,872 B [2][64][156]
  const float* w = (const float*)d_in[0];
  const float* o = (const float*)d_in[1];

  f1_kernel<<<dim3(BATCH * 64), dim3(256), 0, stream>>>(w, o, G, E);
  f2_kernel<<<dim3(BATCH * 157), dim3(256), 0, stream>>>(G, X);
  i1_kernel<<<dim3(BATCH * NB * 40), dim3(1024), 0, stream>>>(X, H);
  i2_kernel<<<dim3(BATCH * NB * 32), dim3(256), 0, stream>>>(H, E);
  finalize_kernel<<<dim3(1), dim3(1024), 0, stream>>>(E, (float*)d_out);
}